// Round 5
// baseline (1246.535 us; speedup 1.0000x reference)
//
#include <hip/hip_runtime.h>
#include <stdint.h>
#include <stddef.h>

#define BATCH 4096
#define HID   1024
#define EMB   64
#define NKH   32      // h K-tiles of 32
#define NSTEP 19
#define NOBS  8
#define WSL   139264  // halfs per 128-pcol slice of Wsw: 34*8*512

typedef _Float16 f16;
typedef _Float16 half8 __attribute__((ext_vector_type(8)));
typedef float    float4v __attribute__((ext_vector_type(4)));

__device__ __forceinline__ float sigm(float x) { return 1.f / (1.f + __expf(-x)); }
__device__ __forceinline__ float tanh_f(float x) { return 1.f - 2.f / (__expf(2.f * x) + 1.f); }

// ---------------------------------------------------------------------------
// Pack W_ih|W_hh -> fragment-major fp16 Wsw[slice][kt][ni][lane][8].
// pcol mapping (gates within a wave's 4 ni tiles):
//   p = bn*256 + wn*64 + g*16 + v ; unit u = bn*64 + wn*16 + v ; orig = g*HID+u
//   i.e. g = (p>>4)&3, u = (p>>8)*64 + ((p>>6)&3)*16 + (p&15)
// k = kt*32 + (lane>>4)*8 + e ; kt 0,1 = emb (W_ih), kt 2..33 = h (W_hh).
// (Mapping is p-global: independent of the M-tiling of the GEMM kernel.)
// ---------------------------------------------------------------------------
__global__ void pack_kernel(const float* __restrict__ W_ih, const float* __restrict__ b_ih,
                            const float* __restrict__ W_hh, const float* __restrict__ b_hh,
                            f16* __restrict__ Wsw, float* __restrict__ bc) {
  int gid = blockIdx.x * blockDim.x + threadIdx.x;  // 32 * WSL
  int tt = gid / WSL;
  int rem = gid - tt * WSL;
  int kt = rem >> 12;
  int ni = (rem >> 9) & 7;
  int lane = (rem >> 3) & 63;
  int e = rem & 7;
  int p = tt * 128 + ni * 16 + (lane & 15);
  int g = (p >> 4) & 3;
  int u = (p >> 8) * 64 + ((p >> 6) & 3) * 16 + (p & 15);
  int orig = g * HID + u;
  int k = kt * 32 + ((lane >> 4) << 3) + e;
  float val = (k < EMB) ? W_ih[orig * EMB + k] : W_hh[orig * HID + (k - EMB)];
  Wsw[gid] = (f16)val;
  if (k == 0) bc[p] = b_ih[orig] + b_hh[orig];
}

// ---------------------------------------------------------------------------
// 128x256-tile fused gates-GEMM + LSTM cell + out-proj partials.
// OCCUPANCY ROUND: wave tile 64x64 (acc[4][4] = 64 regs), 8 waves (2M x 4N),
// grid 512 = 2 blocks/CU, __launch_bounds__(512,4) -> 4 waves/SIMD (was 2).
// Reg-staged double-buffer pipeline from r4 (verified): global->VGPR loads
// for step s+2 issued at step s, ds_write to idle buffer, raw s_barrier with
// lgkmcnt(0)-only drain. 24 chunks of 1KB per step: 8 A + 16 B; 3 per wave.
// ---------------------------------------------------------------------------
__global__ __launch_bounds__(512, 4)
void gemm_cell_kernel(const f16* __restrict__ Xp, const f16* __restrict__ Wsw,
                      const float* __restrict__ bc,
                      f16* __restrict__ c_ws, f16* __restrict__ Xn,
                      float* __restrict__ po_ws, const float* __restrict__ W_out,
                      const float* __restrict__ obs_t, const float* __restrict__ outprev,
                      int mode, const float* __restrict__ W_emb,
                      const float* __restrict__ b_emb) {
  __shared__ f16 smem[24576];  // 48 KiB: 2 bufs x (A 8KB + B 16KB)

  const int tid = threadIdx.x;
  const int lane = tid & 63;
  const int w = tid >> 6;
  const int l15 = lane & 15;
  const int quad = lane >> 4;
  const int wm = w >> 2, wn = w & 3;
  const int sh = wn >> 1, nq = wn & 1;

  // XCD swizzle: XCD x gets bn pair {2x,2x+1} (its B slices stay L2-resident)
  const int id = blockIdx.x;            // 0..511
  const int x = id & 7, rr0 = id >> 3;  // rr0 0..63
  const int bn = x * 2 + (rr0 & 1);     // 0..15
  const int bm = rr0 >> 1;              // 0..31
  const int slice = bn * 2 + sh;        // 128-col slice this wave reads B from

  float4v acc[4][4];
#pragma unroll
  for (int mi = 0; mi < 4; ++mi)
#pragma unroll
    for (int ni = 0; ni < 4; ++ni) acc[mi][ni] = (float4v){0.f, 0.f, 0.f, 0.f};

  // staging registers: 3 chunks/wave (12 VGPR)
  half8 R[3];

  // load K-tile kh (data for step kh+1) into R; plain global->VGPR loads
  auto gload = [&](int kh) {
#pragma unroll
    for (int i = 0; i < 3; ++i) {
      const int c = w * 3 + i;  // 0..23: 0-7 A rowtiles, 8-23 B chunks
      if (c < 8) {
        R[i] = *(const half8*)(Xp + ((size_t)(bm * 8 + c) * NKH + kh) * 512 + lane * 8);
      } else {
        const int cb = c - 8;
        R[i] = *(const half8*)(Wsw + (size_t)(bn * 2 + (cb >> 3)) * WSL +
                               (size_t)(2 + kh) * 4096 + (cb & 7) * 512 + lane * 8);
      }
    }
  };
  // ds_write R into buffer p2 (compiler inserts precise vmcnt waits on R)
  auto dswr = [&](int p2) {
    f16* buf = smem + p2 * 12288;
#pragma unroll
    for (int i = 0; i < 3; ++i)
      *(half8*)(buf + (w * 3 + i) * 512 + lane * 8) = R[i];
  };
  // compute one K-step from LDS base: 4 B frags buffered, A frags on demand
  auto compute = [&](const f16* base) {
    half8 bq[4];
#pragma unroll
    for (int ni = 0; ni < 4; ++ni)
      bq[ni] = *(const half8*)(base + 4096 + (sh * 8 + nq * 4 + ni) * 512 + lane * 8);
    __builtin_amdgcn_s_setprio(1);
#pragma unroll
    for (int mi = 0; mi < 4; ++mi) {
      half8 am = *(const half8*)(base + (wm * 4 + mi) * 512 + lane * 8);
#pragma unroll
      for (int ni = 0; ni < 4; ++ni)
        acc[mi][ni] = __builtin_amdgcn_mfma_f32_16x16x32_f16(am, bq[ni], acc[mi][ni], 0, 0, 0);
    }
    __builtin_amdgcn_s_setprio(0);
  };

  if (mode != 0) gload(0);  // first K-tile loads fly under the emb phase

  // ---- emb phase (K 0..63), A computed in-register, B direct from global ----
  {
    float d0[4], d1[4];
#pragma unroll
    for (int mi = 0; mi < 4; ++mi) {
      const int row = (bm * 8 + wm * 4 + mi) * 16 + l15;
      if (mode <= 1) {
        const float* o = obs_t + (size_t)row * 2;
        d0[mi] = o[BATCH * 2] - o[0];
        d1[mi] = o[BATCH * 2 + 1] - o[1];
      } else {
        d0[mi] = outprev[(size_t)row * 5 + 0];
        d1[mi] = outprev[(size_t)row * 5 + 1];
      }
    }
#pragma unroll
    for (int kt = 0; kt < 2; ++kt) {
      float w0[8], w1[8], be[8];
#pragma unroll
      for (int e = 0; e < 8; ++e) {
        const int j = kt * 32 + quad * 8 + e;
        w0[e] = W_emb[2 * j];
        w1[e] = W_emb[2 * j + 1];
        be[e] = b_emb[j];
      }
      half8 bfe[4];
#pragma unroll
      for (int ni = 0; ni < 4; ++ni)
        bfe[ni] = *(const half8*)(Wsw + (size_t)slice * WSL + kt * 4096 + (nq * 4 + ni) * 512 + lane * 8);
#pragma unroll
      for (int mi = 0; mi < 4; ++mi) {
        half8 ae;
#pragma unroll
        for (int e = 0; e < 8; ++e)
          ae[e] = (f16)fmaxf(d0[mi] * w0[e] + d1[mi] * w1[e] + be[e], 0.f);
#pragma unroll
        for (int ni = 0; ni < 4; ++ni)
          acc[mi][ni] = __builtin_amdgcn_mfma_f32_16x16x32_f16(ae, bfe[ni], acc[mi][ni], 0, 0, 0);
      }
    }
  }

  // ---- h phase: 32 K-steps of 32, reg-staged double-buffer pipeline ----
  // step s reads buf((s-1)&1) = data s; writes data s+1 to the other buf;
  // issues loads for data s+2. Barrier = lgkmcnt(0) + raw s_barrier only.
  if (mode != 0) {
    dswr(0);    // data 1 -> buf0
    gload(1);   // data 2 (WAR on R handled by compiler waitcnts)
    asm volatile("s_waitcnt lgkmcnt(0)" ::: "memory");
    __builtin_amdgcn_sched_barrier(0);
    __builtin_amdgcn_s_barrier();
    for (int s = 1; s <= 32; ++s) {
      if (s < 32) dswr(s & 1);      // data s+1 into idle buffer
      if (s < 31) gload(s + 1);     // data s+2 in flight across this step
      compute(smem + ((s - 1) & 1) * 12288);
      asm volatile("s_waitcnt lgkmcnt(0)" ::: "memory");
      __builtin_amdgcn_sched_barrier(0);
      __builtin_amdgcn_s_barrier();
    }
  }

  // ---- epilogue: lane-local LSTM cell + h write + wn-reduced partials ----
  float bb[4];
#pragma unroll
  for (int ni = 0; ni < 4; ++ni) bb[ni] = bc[bn * 256 + wn * 64 + ni * 16 + l15];
  const int u = bn * 64 + wn * 16 + l15;
  float wo[5];
#pragma unroll
  for (int o = 0; o < 5; ++o) wo[o] = W_out[o * HID + u];

  f16* cbase = c_ws + ((size_t)(bm * 16 + bn) * 512 + tid) * 16;
  half8 cv[2];
  if (mode != 0) {
#pragma unroll
    for (int q = 0; q < 2; ++q) cv[q] = *(const half8*)(cbase + q * 8);
  }

  __syncthreads();                 // staged LDS no longer needed; reuse as pol
  float* pol = (float*)smem;       // [128 rows][4 wn][5]

#pragma unroll
  for (int mi = 0; mi < 4; ++mi) {
#pragma unroll
    for (int r = 0; r < 4; ++r) {
      const int rl = wm * 64 + mi * 16 + quad * 4 + r;  // row within block
      const int row = bm * 128 + rl;
      const int ci = mi * 4 + r;                        // 0..15
      float gi = acc[mi][0][r] + bb[0];
      float gf = acc[mi][1][r] + bb[1];
      float gg = acc[mi][2][r] + bb[2];
      float go = acc[mi][3][r] + bb[3];
      float co = (mode == 0) ? 0.f : (float)cv[ci >> 3][ci & 7];
      float cn = sigm(gf) * co + sigm(gi) * tanh_f(gg);
      cv[ci >> 3][ci & 7] = (f16)cn;
      float h = sigm(go) * tanh_f(cn);
      // h col = u ; frag index kh = u>>5 = slice ; A-frag layout for next step
      Xn[(((size_t)(row >> 4) * NKH + slice) * 64 + (quad * 4 + r) +
          16 * ((wn & 1) * 2 + (l15 >> 3))) * 8 + (l15 & 7)] = (f16)h;
      float pa[5];
#pragma unroll
      for (int o = 0; o < 5; ++o) pa[o] = h * wo[o];
#pragma unroll
      for (int o = 0; o < 5; ++o) {
        pa[o] += __shfl_xor(pa[o], 1, 64);
        pa[o] += __shfl_xor(pa[o], 2, 64);
        pa[o] += __shfl_xor(pa[o], 4, 64);
        pa[o] += __shfl_xor(pa[o], 8, 64);
      }
      if (l15 == 0) {
#pragma unroll
        for (int o = 0; o < 5; ++o) pol[(rl * 4 + wn) * 5 + o] = pa[o];
      }
    }
  }
#pragma unroll
  for (int q = 0; q < 2; ++q) *(half8*)(cbase + q * 8) = cv[q];

  __syncthreads();
  for (int idx = tid; idx < 640; idx += 512) {
    const int rl = idx / 5, o = idx - rl * 5;
    float s = 0.f;
#pragma unroll
    for (int j = 0; j < 4; ++j) s += pol[(rl * 4 + j) * 5 + o];
    po_ws[((size_t)bn * BATCH + bm * 128 + rl) * 5 + o] = s;
  }
}

// ---------------------------------------------------------------------------
// Reduce out-proj partials over 16 bn slices, add bias, write out.
// 128 blocks x 256 thr, 32 rows per block.
// ---------------------------------------------------------------------------
__global__ __launch_bounds__(256)
void reduce_kernel(const float* __restrict__ po_ws, const float* __restrict__ b_out,
                   float* __restrict__ out_t) {
  const int tid = threadIdx.x;
  const int r0 = blockIdx.x * 32;
  if (tid < 160) {
    const int rowl = tid / 5, o = tid - rowl * 5;
    const int row = r0 + rowl;
    float s = 0.f;
#pragma unroll
    for (int g = 0; g < 16; ++g) s += po_ws[((size_t)g * BATCH + row) * 5 + o];
    out_t[(size_t)row * 5 + o] = s + b_out[o];
  }
}

// ---------------------------------------------------------------------------
extern "C" void kernel_launch(void* const* d_in, const int* in_sizes, int n_in,
                              void* d_out, int out_size, void* d_ws, size_t ws_size,
                              hipStream_t stream) {
  const float* observed = (const float*)d_in[0];
  const float* W_emb = (const float*)d_in[1];
  const float* b_emb = (const float*)d_in[2];
  const float* W_ih = (const float*)d_in[3];
  const float* b_ih = (const float*)d_in[4];
  const float* W_hh = (const float*)d_in[5];
  const float* b_hh = (const float*)d_in[6];
  const float* W_out = (const float*)d_in[7];
  const float* b_out = (const float*)d_in[8];
  float* out = (float*)d_out;

  uint8_t* ws = (uint8_t*)d_ws;
  const size_t WSW_BYTES = (size_t)32 * WSL * sizeof(f16);           // 8,912,896
  const size_t XH_BYTES = (size_t)256 * NKH * 64 * 8 * sizeof(f16);  // 8 MiB
  f16* Wsw = (f16*)ws;
  float* bc = (float*)(ws + WSW_BYTES);
  f16* X0 = (f16*)(ws + WSW_BYTES + 16384);
  f16* X1 = (f16*)(ws + WSW_BYTES + 16384 + XH_BYTES);
  f16* c_ws = (f16*)(ws + WSW_BYTES + 16384 + 2 * XH_BYTES);
  float* po_ws = (float*)(ws + WSW_BYTES + 16384 + 2 * XH_BYTES + (size_t)BATCH * HID * 2);

  pack_kernel<<<(32 * WSL) / 256, 256, 0, stream>>>(W_ih, b_ih, W_hh, b_hh, Wsw, bc);

  for (int t = 0; t < NSTEP; ++t) {
    f16* Xc = (t & 1) ? X1 : X0;  // h(t) written here
    f16* Xq = (t & 1) ? X0 : X1;  // h(t-1)
    const int mode = (t == 0) ? 0 : (t < NOBS ? 1 : 2);
    gemm_cell_kernel<<<512, 512, 0, stream>>>(
        Xq, Wsw, bc, c_ws, Xc, po_ws, W_out,
        observed + (size_t)t * BATCH * 2, out + (size_t)(t - 1) * BATCH * 5,
        mode, W_emb, b_emb);
    reduce_kernel<<<BATCH / 32, 256, 0, stream>>>(po_ws, b_out, out + (size_t)t * BATCH * 5);
  }
}

// Round 7
// 1134.599 us; speedup vs baseline: 1.0987x; 1.0987x over previous
//
#include <hip/hip_runtime.h>
#include <stdint.h>
#include <stddef.h>

#define BATCH 4096
#define HID   1024
#define EMB   64
#define NKH   32      // h K-tiles of 32
#define NSTEP 19
#define NOBS  8
#define WSL   139264  // halfs per 128-pcol slice of Wsw: 34*8*512

typedef _Float16 f16;
typedef _Float16 half8 __attribute__((ext_vector_type(8)));
typedef float    float4v __attribute__((ext_vector_type(4)));

__device__ __forceinline__ float sigm(float x) { return 1.f / (1.f + __expf(-x)); }
__device__ __forceinline__ float tanh_f(float x) { return 1.f - 2.f / (__expf(2.f * x) + 1.f); }

// ---------------------------------------------------------------------------
// Pack W_ih|W_hh -> fragment-major fp16 Wsw[slice][kt][ni][lane][8].
// pcol mapping (gates within a wave's 4 ni tiles):
//   p = bn*256 + wn*64 + g*16 + v ; unit u = bn*64 + wn*16 + v ; orig = g*HID+u
//   i.e. g = (p>>4)&3, u = (p>>8)*64 + ((p>>6)&3)*16 + (p&15)
// k = kt*32 + (lane>>4)*8 + e ; kt 0,1 = emb (W_ih), kt 2..33 = h (W_hh).
// (Mapping is p-global: independent of the M-tiling of the GEMM kernel.)
// ---------------------------------------------------------------------------
__global__ void pack_kernel(const float* __restrict__ W_ih, const float* __restrict__ b_ih,
                            const float* __restrict__ W_hh, const float* __restrict__ b_hh,
                            f16* __restrict__ Wsw, float* __restrict__ bc) {
  int gid = blockIdx.x * blockDim.x + threadIdx.x;  // 32 * WSL
  int tt = gid / WSL;
  int rem = gid - tt * WSL;
  int kt = rem >> 12;
  int ni = (rem >> 9) & 7;
  int lane = (rem >> 3) & 63;
  int e = rem & 7;
  int p = tt * 128 + ni * 16 + (lane & 15);
  int g = (p >> 4) & 3;
  int u = (p >> 8) * 64 + ((p >> 6) & 3) * 16 + (p & 15);
  int orig = g * HID + u;
  int k = kt * 32 + ((lane >> 4) << 3) + e;
  float val = (k < EMB) ? W_ih[orig * EMB + k] : W_hh[orig * HID + (k - EMB)];
  Wsw[gid] = (f16)val;
  if (k == 0) bc[p] = b_ih[orig] + b_hh[orig];
}

// ---------------------------------------------------------------------------
// Fused gates-GEMM + LSTM cell + out-proj partials. NO LDS / NO BARRIERS in
// the K-loop (r0 structure, the fastest measured): each wave fully
// independent, register ping-pong double-buffer, loads direct from L2.
// Wave tile 64x64 (acc[4][4] = 64 regs) -> ~150 VGPR -> 3 waves/SIMD
// (__launch_bounds__(256,3)); waves self-stagger, no phase lockstep.
// Block: 4 waves stacked in N (share A-lines); block tile 64 rows x 256 pcols.
// Grid 1024 = 64 bm x 16 bn, 2D XCD swizzle keeps B slices L2-resident.
// ---------------------------------------------------------------------------
__global__ __launch_bounds__(256, 3)
void gemm_cell_kernel(const f16* __restrict__ Xp, const f16* __restrict__ Wsw,
                      const float* __restrict__ bc,
                      f16* __restrict__ c_ws, f16* __restrict__ Xn,
                      float* __restrict__ po_ws, const float* __restrict__ W_out,
                      const float* __restrict__ obs_t, const float* __restrict__ outprev,
                      int mode, const float* __restrict__ W_emb,
                      const float* __restrict__ b_emb) {
  __shared__ float pol[64 * 4 * 5];  // 5 KiB, epilogue only

  const int tid = threadIdx.x;
  const int lane = tid & 63;
  const int wn = tid >> 6;           // wave 0..3 = N-position
  const int l15 = lane & 15;
  const int quad = lane >> 4;
  const int sh = wn >> 1, nq = wn & 1;

  // XCD swizzle: XCD x gets bn pair {2x,2x+1} (its B slices stay L2-resident)
  const int id = blockIdx.x;            // 0..1023
  const int x = id & 7, rr0 = id >> 3;  // rr0 0..127
  const int bn = x * 2 + (rr0 & 1);     // 0..15
  const int bm = rr0 >> 1;              // 0..63
  const int slice = bn * 2 + sh;        // 128-col slice this wave reads B from

  float4v acc[4][4];
#pragma unroll
  for (int mi = 0; mi < 4; ++mi)
#pragma unroll
    for (int ni = 0; ni < 4; ++ni) acc[mi][ni] = (float4v){0.f, 0.f, 0.f, 0.f};

  const f16* aB = Xp + (size_t)(bm * 4) * (NKH * 512) + lane * 8;  // +mi*NKH*512 +kh*512
  const f16* bB = Wsw + (size_t)slice * WSL + (size_t)2 * 4096 + (nq * 4) * 512 + lane * 8;
                                                                   // +kh*4096 +ni*512

  // ---- emb phase (K 0..63), A computed in-register, B direct from global ----
  {
    float d0[4], d1[4];
#pragma unroll
    for (int mi = 0; mi < 4; ++mi) {
      const int row = (bm * 4 + mi) * 16 + l15;
      if (mode <= 1) {
        const float* o = obs_t + (size_t)row * 2;
        d0[mi] = o[BATCH * 2] - o[0];
        d1[mi] = o[BATCH * 2 + 1] - o[1];
      } else {
        d0[mi] = outprev[(size_t)row * 5 + 0];
        d1[mi] = outprev[(size_t)row * 5 + 1];
      }
    }
#pragma unroll
    for (int kt = 0; kt < 2; ++kt) {
      float w0[8], w1[8], be[8];
#pragma unroll
      for (int e = 0; e < 8; ++e) {
        const int j = kt * 32 + quad * 8 + e;
        w0[e] = W_emb[2 * j];
        w1[e] = W_emb[2 * j + 1];
        be[e] = b_emb[j];
      }
      half8 bfe[4];
#pragma unroll
      for (int ni = 0; ni < 4; ++ni)
        bfe[ni] = *(const half8*)(Wsw + (size_t)slice * WSL + kt * 4096 + (nq * 4 + ni) * 512 + lane * 8);
#pragma unroll
      for (int mi = 0; mi < 4; ++mi) {
        half8 ae;
#pragma unroll
        for (int e = 0; e < 8; ++e)
          ae[e] = (f16)fmaxf(d0[mi] * w0[e] + d1[mi] * w1[e] + be[e], 0.f);
#pragma unroll
        for (int ni = 0; ni < 4; ++ni)
          acc[mi][ni] = __builtin_amdgcn_mfma_f32_16x16x32_f16(ae, bfe[ni], acc[mi][ni], 0, 0, 0);
      }
    }
  }

  // ---- h phase (K-tiles 0..31), register ping-pong double-buffer ----
  if (mode != 0) {
    half8 afA[4], bfA[4], afB[4], bfB[4];
#define LOADF(af, bf, kh)                                                      \
  do {                                                                         \
    _Pragma("unroll") for (int mi = 0; mi < 4; ++mi)                           \
        af[mi] = *(const half8*)(aB + mi * (NKH * 512) + (kh) * 512);          \
    _Pragma("unroll") for (int ni = 0; ni < 4; ++ni)                           \
        bf[ni] = *(const half8*)(bB + (size_t)(kh) * 4096 + ni * 512);         \
  } while (0)
#define MFMA_ALL(af, bf)                                                       \
  do {                                                                         \
    __builtin_amdgcn_s_setprio(1);                                             \
    _Pragma("unroll") for (int mi = 0; mi < 4; ++mi)                           \
    _Pragma("unroll") for (int ni = 0; ni < 4; ++ni)                           \
        acc[mi][ni] =                                                          \
            __builtin_amdgcn_mfma_f32_16x16x32_f16(af[mi], bf[ni], acc[mi][ni], 0, 0, 0); \
    __builtin_amdgcn_s_setprio(0);                                             \
  } while (0)
    LOADF(afA, bfA, 0);
    for (int i = 0; i < NKH / 2; ++i) {
      const int k1 = 2 * i + 1;
      LOADF(afB, bfB, k1);
      MFMA_ALL(afA, bfA);
      if (k1 + 1 < NKH) LOADF(afA, bfA, k1 + 1);
      MFMA_ALL(afB, bfB);
    }
#undef LOADF
#undef MFMA_ALL
  }

  // ---- epilogue: lane-local LSTM cell + h write + wn-reduced partials ----
  float bb[4];
#pragma unroll
  for (int ni = 0; ni < 4; ++ni) bb[ni] = bc[bn * 256 + wn * 64 + ni * 16 + l15];
  const int u = bn * 64 + wn * 16 + l15;
  float wo[5];
#pragma unroll
  for (int o = 0; o < 5; ++o) wo[o] = W_out[o * HID + u];

  f16* cbase = c_ws + ((size_t)(bm * 16 + bn) * 256 + tid) * 16;
  half8 cv[2];
  if (mode != 0) {
#pragma unroll
    for (int q = 0; q < 2; ++q) cv[q] = *(const half8*)(cbase + q * 8);
  }

#pragma unroll
  for (int mi = 0; mi < 4; ++mi) {
#pragma unroll
    for (int r = 0; r < 4; ++r) {
      const int rl = mi * 16 + quad * 4 + r;  // row within block (0..63)
      const int row = bm * 64 + rl;
      const int ci = mi * 4 + r;              // 0..15
      float gi = acc[mi][0][r] + bb[0];
      float gf = acc[mi][1][r] + bb[1];
      float gg = acc[mi][2][r] + bb[2];
      float go = acc[mi][3][r] + bb[3];
      float co = (mode == 0) ? 0.f : (float)cv[ci >> 3][ci & 7];
      float cn = sigm(gf) * co + sigm(gi) * tanh_f(gg);
      cv[ci >> 3][ci & 7] = (f16)cn;
      float h = sigm(go) * tanh_f(cn);
      // h col = u ; frag index kh = u>>5 = slice ; A-frag layout for next step
      Xn[(((size_t)(row >> 4) * NKH + slice) * 64 + (quad * 4 + r) +
          16 * ((wn & 1) * 2 + (l15 >> 3))) * 8 + (l15 & 7)] = (f16)h;
      float pa[5];
#pragma unroll
      for (int o = 0; o < 5; ++o) pa[o] = h * wo[o];
#pragma unroll
      for (int o = 0; o < 5; ++o) {
        pa[o] += __shfl_xor(pa[o], 1, 64);
        pa[o] += __shfl_xor(pa[o], 2, 64);
        pa[o] += __shfl_xor(pa[o], 4, 64);
        pa[o] += __shfl_xor(pa[o], 8, 64);
      }
      if (l15 == 0) {
#pragma unroll
        for (int o = 0; o < 5; ++o) pol[(rl * 4 + wn) * 5 + o] = pa[o];
      }
    }
  }
#pragma unroll
  for (int q = 0; q < 2; ++q) *(half8*)(cbase + q * 8) = cv[q];

  __syncthreads();
  for (int idx = tid; idx < 320; idx += 256) {
    const int rl = idx / 5, o = idx - rl * 5;
    float s = 0.f;
#pragma unroll
    for (int j = 0; j < 4; ++j) s += pol[(rl * 4 + j) * 5 + o];
    po_ws[((size_t)bn * BATCH + bm * 64 + rl) * 5 + o] = s;
  }
}

// ---------------------------------------------------------------------------
// Reduce out-proj partials over 16 bn slices, add bias, write out.
// 128 blocks x 256 thr, 32 rows per block.
// ---------------------------------------------------------------------------
__global__ __launch_bounds__(256)
void reduce_kernel(const float* __restrict__ po_ws, const float* __restrict__ b_out,
                   float* __restrict__ out_t) {
  const int tid = threadIdx.x;
  const int r0 = blockIdx.x * 32;
  if (tid < 160) {
    const int rowl = tid / 5, o = tid - rowl * 5;
    const int row = r0 + rowl;
    float s = 0.f;
#pragma unroll
    for (int g = 0; g < 16; ++g) s += po_ws[((size_t)g * BATCH + row) * 5 + o];
    out_t[(size_t)row * 5 + o] = s + b_out[o];
  }
}

// ---------------------------------------------------------------------------
extern "C" void kernel_launch(void* const* d_in, const int* in_sizes, int n_in,
                              void* d_out, int out_size, void* d_ws, size_t ws_size,
                              hipStream_t stream) {
  const float* observed = (const float*)d_in[0];
  const float* W_emb = (const float*)d_in[1];
  const float* b_emb = (const float*)d_in[2];
  const float* W_ih = (const float*)d_in[3];
  const float* b_ih = (const float*)d_in[4];
  const float* W_hh = (const float*)d_in[5];
  const float* b_hh = (const float*)d_in[6];
  const float* W_out = (const float*)d_in[7];
  const float* b_out = (const float*)d_in[8];
  float* out = (float*)d_out;

  uint8_t* ws = (uint8_t*)d_ws;
  const size_t WSW_BYTES = (size_t)32 * WSL * sizeof(f16);           // 8,912,896
  const size_t XH_BYTES = (size_t)256 * NKH * 64 * 8 * sizeof(f16);  // 8 MiB
  f16* Wsw = (f16*)ws;
  float* bc = (float*)(ws + WSW_BYTES);
  f16* X0 = (f16*)(ws + WSW_BYTES + 16384);
  f16* X1 = (f16*)(ws + WSW_BYTES + 16384 + XH_BYTES);
  f16* c_ws = (f16*)(ws + WSW_BYTES + 16384 + 2 * XH_BYTES);
  float* po_ws = (float*)(ws + WSW_BYTES + 16384 + 2 * XH_BYTES + (size_t)BATCH * HID * 2);

  pack_kernel<<<(32 * WSL) / 256, 256, 0, stream>>>(W_ih, b_ih, W_hh, b_hh, Wsw, bc);

  for (int t = 0; t < NSTEP; ++t) {
    f16* Xc = (t & 1) ? X1 : X0;  // h(t) written here
    f16* Xq = (t & 1) ? X0 : X1;  // h(t-1)
    const int mode = (t == 0) ? 0 : (t < NOBS ? 1 : 2);
    gemm_cell_kernel<<<1024, 256, 0, stream>>>(
        Xq, Wsw, bc, c_ws, Xc, po_ws, W_out,
        observed + (size_t)t * BATCH * 2, out + (size_t)(t - 1) * BATCH * 5,
        mode, W_emb, b_emb);
    reduce_kernel<<<BATCH / 32, 256, 0, stream>>>(po_ws, b_out, out + (size_t)t * BATCH * 5);
  }
}

// Round 8
// 1123.874 us; speedup vs baseline: 1.1091x; 1.0095x over previous
//
#include <hip/hip_runtime.h>
#include <stdint.h>
#include <stddef.h>

#define BATCH 4096
#define HID   1024
#define EMB   64
#define NKH   32      // h K-tiles of 32
#define NSTEP 19
#define NOBS  8
#define WSL   139264  // halfs per 128-pcol slice of Wsw: 34*8*512

typedef _Float16 f16;
typedef _Float16 half8 __attribute__((ext_vector_type(8)));
typedef float    float4v __attribute__((ext_vector_type(4)));

__device__ __forceinline__ float sigm(float x) { return 1.f / (1.f + __expf(-x)); }
__device__ __forceinline__ float tanh_f(float x) { return 1.f - 2.f / (__expf(2.f * x) + 1.f); }

// ---------------------------------------------------------------------------
// Pack W_ih|W_hh -> fragment-major fp16 Wsw[slice][kt][ni][lane][8].
// pcol mapping (gates within a wave's 4 ni tiles):
//   p = bn*256 + wn*64 + g*16 + v ; unit u = bn*64 + wn*16 + v ; orig = g*HID+u
//   i.e. g = (p>>4)&3, u = (p>>8)*64 + ((p>>6)&3)*16 + (p&15)
// k = kt*32 + (lane>>4)*8 + e ; kt 0,1 = emb (W_ih), kt 2..33 = h (W_hh).
// ---------------------------------------------------------------------------
__global__ void pack_kernel(const float* __restrict__ W_ih, const float* __restrict__ b_ih,
                            const float* __restrict__ W_hh, const float* __restrict__ b_hh,
                            f16* __restrict__ Wsw, float* __restrict__ bc) {
  int gid = blockIdx.x * blockDim.x + threadIdx.x;  // 32 * WSL
  int tt = gid / WSL;
  int rem = gid - tt * WSL;
  int kt = rem >> 12;
  int ni = (rem >> 9) & 7;
  int lane = (rem >> 3) & 63;
  int e = rem & 7;
  int p = tt * 128 + ni * 16 + (lane & 15);
  int g = (p >> 4) & 3;
  int u = (p >> 8) * 64 + ((p >> 6) & 3) * 16 + (p & 15);
  int orig = g * HID + u;
  int k = kt * 32 + ((lane >> 4) << 3) + e;
  float val = (k < EMB) ? W_ih[orig * EMB + k] : W_hh[orig * HID + (k - EMB)];
  Wsw[gid] = (f16)val;
  if (k == 0) bc[p] = b_ih[orig] + b_hh[orig];
}

// ---------------------------------------------------------------------------
// Fused gates-GEMM + LSTM cell. NO LDS / NO BARRIERS anywhere; K-loop fully
// statically unrolled (all load offsets compile-time -> minimal VALU address
// arithmetic); 2-deep register ping-pong. Epilogue = cell + c/Xn writes ONLY
// (out-projection moved to out_kernel). Wave tile 64x64, 4 waves stacked in
// N, grid 1024 = 64 bm x 16 bn, 2D XCD swizzle keeps B slices L2-resident.
// ---------------------------------------------------------------------------
__global__ __launch_bounds__(256, 3)
void gemm_cell_kernel(const f16* __restrict__ Xp, const f16* __restrict__ Wsw,
                      const float* __restrict__ bc,
                      f16* __restrict__ c_ws, f16* __restrict__ Xn,
                      const float* __restrict__ obs_t, const float* __restrict__ outprev,
                      int mode, const float* __restrict__ W_emb,
                      const float* __restrict__ b_emb) {
  const int tid = threadIdx.x;
  const int lane = tid & 63;
  const int wn = tid >> 6;           // wave 0..3 = N-position
  const int l15 = lane & 15;
  const int quad = lane >> 4;
  const int sh = wn >> 1, nq = wn & 1;

  // XCD swizzle: XCD x gets bn pair {2x,2x+1} (its B slices stay L2-resident)
  const int id = blockIdx.x;            // 0..1023
  const int x = id & 7, rr0 = id >> 3;  // rr0 0..127
  const int bn = x * 2 + (rr0 & 1);     // 0..15
  const int bm = rr0 >> 1;              // 0..63
  const int slice = bn * 2 + sh;        // 128-col slice this wave reads B from

  float4v acc[4][4];
#pragma unroll
  for (int mi = 0; mi < 4; ++mi)
#pragma unroll
    for (int ni = 0; ni < 4; ++ni) acc[mi][ni] = (float4v){0.f, 0.f, 0.f, 0.f};

  const f16* aB = Xp + (size_t)(bm * 4) * (NKH * 512) + lane * 8;  // +mi*NKH*512 +kh*512
  const f16* bB = Wsw + (size_t)slice * WSL + 2 * 4096 + (nq * 4) * 512 + lane * 8;
                                                                   // +kh*4096 +ni*512

  // ---- emb phase (K 0..63), A computed in-register, B direct from global ----
  {
    float d0[4], d1[4];
#pragma unroll
    for (int mi = 0; mi < 4; ++mi) {
      const int row = (bm * 4 + mi) * 16 + l15;
      if (mode <= 1) {
        const float* o = obs_t + (size_t)row * 2;
        d0[mi] = o[BATCH * 2] - o[0];
        d1[mi] = o[BATCH * 2 + 1] - o[1];
      } else {
        d0[mi] = outprev[(size_t)row * 5 + 0];
        d1[mi] = outprev[(size_t)row * 5 + 1];
      }
    }
#pragma unroll
    for (int kt = 0; kt < 2; ++kt) {
      float w0[8], w1[8], be[8];
#pragma unroll
      for (int e = 0; e < 8; ++e) {
        const int j = kt * 32 + quad * 8 + e;
        w0[e] = W_emb[2 * j];
        w1[e] = W_emb[2 * j + 1];
        be[e] = b_emb[j];
      }
      half8 bfe[4];
#pragma unroll
      for (int ni = 0; ni < 4; ++ni)
        bfe[ni] = *(const half8*)(Wsw + (size_t)slice * WSL + kt * 4096 + (nq * 4 + ni) * 512 + lane * 8);
#pragma unroll
      for (int mi = 0; mi < 4; ++mi) {
        half8 ae;
#pragma unroll
        for (int e = 0; e < 8; ++e)
          ae[e] = (f16)fmaxf(d0[mi] * w0[e] + d1[mi] * w1[e] + be[e], 0.f);
#pragma unroll
        for (int ni = 0; ni < 4; ++ni)
          acc[mi][ni] = __builtin_amdgcn_mfma_f32_16x16x32_f16(ae, bfe[ni], acc[mi][ni], 0, 0, 0);
      }
    }
  }

  // ---- h phase (K-tiles 0..31): fully static unroll, 2-deep reg ping-pong ----
  if (mode != 0) {
    half8 af[2][4], bf[2][4];
#define LOADT(buf, kh)                                                         \
  do {                                                                         \
    _Pragma("unroll") for (int mi = 0; mi < 4; ++mi)                           \
        af[buf][mi] = *(const half8*)(aB + mi * (NKH * 512) + (kh) * 512);     \
    _Pragma("unroll") for (int ni = 0; ni < 4; ++ni)                           \
        bf[buf][ni] = *(const half8*)(bB + (kh) * 4096 + ni * 512);            \
  } while (0)
    LOADT(0, 0);
#pragma unroll
    for (int kh = 0; kh < NKH; ++kh) {
      if (kh + 1 < NKH) LOADT((kh + 1) & 1, kh + 1);
      __builtin_amdgcn_s_setprio(1);
#pragma unroll
      for (int mi = 0; mi < 4; ++mi)
#pragma unroll
        for (int ni = 0; ni < 4; ++ni)
          acc[mi][ni] = __builtin_amdgcn_mfma_f32_16x16x32_f16(af[kh & 1][mi], bf[kh & 1][ni],
                                                               acc[mi][ni], 0, 0, 0);
      __builtin_amdgcn_s_setprio(0);
    }
#undef LOADT
  }

  // ---- epilogue: lane-local LSTM cell + c/Xn writes (no out-proj here) ----
  float bb[4];
#pragma unroll
  for (int ni = 0; ni < 4; ++ni) bb[ni] = bc[bn * 256 + wn * 64 + ni * 16 + l15];

  f16* cbase = c_ws + ((size_t)(bm * 16 + bn) * 256 + tid) * 16;
  half8 cv[2];
  if (mode != 0) {
#pragma unroll
    for (int q = 0; q < 2; ++q) cv[q] = *(const half8*)(cbase + q * 8);
  }

#pragma unroll
  for (int mi = 0; mi < 4; ++mi) {
#pragma unroll
    for (int r = 0; r < 4; ++r) {
      const int row = bm * 64 + mi * 16 + quad * 4 + r;
      const int ci = mi * 4 + r;              // 0..15
      float gi = acc[mi][0][r] + bb[0];
      float gf = acc[mi][1][r] + bb[1];
      float gg = acc[mi][2][r] + bb[2];
      float go = acc[mi][3][r] + bb[3];
      float co = (mode == 0) ? 0.f : (float)cv[ci >> 3][ci & 7];
      float cn = sigm(gf) * co + sigm(gi) * tanh_f(gg);
      cv[ci >> 3][ci & 7] = (f16)cn;
      float h = sigm(go) * tanh_f(cn);
      // h col = u = bn*64+wn*16+l15 ; frag index kh = u>>5 = slice
      Xn[(((size_t)(row >> 4) * NKH + slice) * 64 + (quad * 4 + r) +
          16 * ((wn & 1) * 2 + (l15 >> 3))) * 8 + (l15 & 7)] = (f16)h;
    }
  }
#pragma unroll
  for (int q = 0; q < 2; ++q) *(half8*)(cbase + q * 8) = cv[q];
}

// ---------------------------------------------------------------------------
// out[row][o] = b_out[o] + sum_u h[row][u] * W_out[o][u], reading h from the
// Xn fragment layout. One wave per row; lane covers u-chunks lane and lane+64.
// Grid 1024 x 256 (4 waves/block).
// h[row][u] = Xn[(((row>>4)*NKH + (u>>5))*64 + (row&15)
//                 + 16*(((u>>4)&1)*2 + ((u>>3)&1)))*8 + (u&7)]
// ---------------------------------------------------------------------------
__global__ __launch_bounds__(256)
void out_kernel(const f16* __restrict__ Xh, const float* __restrict__ W_out,
                const float* __restrict__ b_out, float* __restrict__ out_t) {
  const int tid = threadIdx.x;
  const int lane = tid & 63;
  const int w = tid >> 6;
  const int row = blockIdx.x * 4 + w;  // 0..4095

  float s[5] = {0.f, 0.f, 0.f, 0.f, 0.f};
#pragma unroll
  for (int half = 0; half < 2; ++half) {
    const int u0 = (lane + half * 64) * 8;  // chunk of 8 consecutive u
    const f16* hp = Xh + (((size_t)(row >> 4) * NKH + (u0 >> 5)) * 64 + (row & 15) +
                          16 * (((u0 >> 4) & 1) * 2 + ((u0 >> 3) & 1))) * 8;
    half8 hv = *(const half8*)hp;
#pragma unroll
    for (int o = 0; o < 5; ++o) {
      const float* wp = W_out + o * HID + u0;
      float acc = 0.f;
#pragma unroll
      for (int e = 0; e < 8; ++e) acc += (float)hv[e] * wp[e];
      s[o] += acc;
    }
  }
#pragma unroll
  for (int o = 0; o < 5; ++o) {
    s[o] += __shfl_xor(s[o], 1, 64);
    s[o] += __shfl_xor(s[o], 2, 64);
    s[o] += __shfl_xor(s[o], 4, 64);
    s[o] += __shfl_xor(s[o], 8, 64);
    s[o] += __shfl_xor(s[o], 16, 64);
    s[o] += __shfl_xor(s[o], 32, 64);
  }
  if (lane == 0) {
#pragma unroll
    for (int o = 0; o < 5; ++o) out_t[(size_t)row * 5 + o] = s[o] + b_out[o];
  }
}

// ---------------------------------------------------------------------------
extern "C" void kernel_launch(void* const* d_in, const int* in_sizes, int n_in,
                              void* d_out, int out_size, void* d_ws, size_t ws_size,
                              hipStream_t stream) {
  const float* observed = (const float*)d_in[0];
  const float* W_emb = (const float*)d_in[1];
  const float* b_emb = (const float*)d_in[2];
  const float* W_ih = (const float*)d_in[3];
  const float* b_ih = (const float*)d_in[4];
  const float* W_hh = (const float*)d_in[5];
  const float* b_hh = (const float*)d_in[6];
  const float* W_out = (const float*)d_in[7];
  const float* b_out = (const float*)d_in[8];
  float* out = (float*)d_out;

  uint8_t* ws = (uint8_t*)d_ws;
  const size_t WSW_BYTES = (size_t)32 * WSL * sizeof(f16);           // 8,912,896
  const size_t XH_BYTES = (size_t)256 * NKH * 64 * 8 * sizeof(f16);  // 8 MiB
  f16* Wsw = (f16*)ws;
  float* bc = (float*)(ws + WSW_BYTES);
  f16* X0 = (f16*)(ws + WSW_BYTES + 16384);
  f16* X1 = (f16*)(ws + WSW_BYTES + 16384 + XH_BYTES);
  f16* c_ws = (f16*)(ws + WSW_BYTES + 16384 + 2 * XH_BYTES);

  pack_kernel<<<(32 * WSL) / 256, 256, 0, stream>>>(W_ih, b_ih, W_hh, b_hh, Wsw, bc);

  for (int t = 0; t < NSTEP; ++t) {
    f16* Xc = (t & 1) ? X1 : X0;  // h(t) written here
    f16* Xq = (t & 1) ? X0 : X1;  // h(t-1)
    const int mode = (t == 0) ? 0 : (t < NOBS ? 1 : 2);
    gemm_cell_kernel<<<1024, 256, 0, stream>>>(
        Xq, Wsw, bc, c_ws, Xc,
        observed + (size_t)t * BATCH * 2, out + (size_t)(t - 1) * BATCH * 5,
        mode, W_emb, b_emb);
    out_kernel<<<BATCH / 4, 256, 0, stream>>>(Xc, W_out, b_out, out + (size_t)t * BATCH * 5);
  }
}

// Round 9
// 1086.226 us; speedup vs baseline: 1.1476x; 1.0347x over previous
//
#include <hip/hip_runtime.h>
#include <stdint.h>
#include <stddef.h>

#define BATCH 4096
#define HID   1024
#define EMB   64
#define NKH   32      // h K-tiles of 32
#define NSTEP 19
#define NOBS  8
#define WSL   139264  // halfs per 128-pcol slice of Wsw: 34*8*512

typedef _Float16 f16;
typedef _Float16 half8 __attribute__((ext_vector_type(8)));
typedef float    float4v __attribute__((ext_vector_type(4)));

__device__ __forceinline__ float sigm(float x) { return 1.f / (1.f + __expf(-x)); }
__device__ __forceinline__ float tanh_f(float x) { return 1.f - 2.f / (__expf(2.f * x) + 1.f); }

// ---------------------------------------------------------------------------
// Pack W_ih|W_hh -> fragment-major fp16 Wsw[slice][kt][ni][lane][8].
// pcol mapping (gates within a wave's 4 ni tiles):
//   p = bn*256 + wn*64 + g*16 + v ; unit u = bn*64 + wn*16 + v ; orig = g*HID+u
//   i.e. g = (p>>4)&3, u = (p>>8)*64 + ((p>>6)&3)*16 + (p&15)
// k = kt*32 + (lane>>4)*8 + e ; kt 0,1 = emb (W_ih), kt 2..33 = h (W_hh).
// ---------------------------------------------------------------------------
__global__ void pack_kernel(const float* __restrict__ W_ih, const float* __restrict__ b_ih,
                            const float* __restrict__ W_hh, const float* __restrict__ b_hh,
                            f16* __restrict__ Wsw, float* __restrict__ bc) {
  int gid = blockIdx.x * blockDim.x + threadIdx.x;  // 32 * WSL
  int tt = gid / WSL;
  int rem = gid - tt * WSL;
  int kt = rem >> 12;
  int ni = (rem >> 9) & 7;
  int lane = (rem >> 3) & 63;
  int e = rem & 7;
  int p = tt * 128 + ni * 16 + (lane & 15);
  int g = (p >> 4) & 3;
  int u = (p >> 8) * 64 + ((p >> 6) & 3) * 16 + (p & 15);
  int orig = g * HID + u;
  int k = kt * 32 + ((lane >> 4) << 3) + e;
  float val = (k < EMB) ? W_ih[orig * EMB + k] : W_hh[orig * HID + (k - EMB)];
  Wsw[gid] = (f16)val;
  if (k == 0) bc[p] = b_ih[orig] + b_hh[orig];
}

// ---------------------------------------------------------------------------
// Fused gates-GEMM + LSTM cell. NO LDS / NO BARRIERS anywhere; K-loop fully
// statically unrolled, 2-deep register ping-pong (r8 structure, verified).
// ROUND 9 CHANGE (only): XCD reuse partition. Old swizzle gave each XCD
// 2 bn x 64 bm -> A working set 8 MB > 4 MB L2 -> A thrashed to L3 (~44 MB
// FETCH). New: XCD x owns bm range of 16 (A 2 MB, L2-resident) x bn range
// of 8 (B 4.4 MB); within XCD, bn walks fastest. Footprint 6.4 MB.
// ---------------------------------------------------------------------------
__global__ __launch_bounds__(256, 3)
void gemm_cell_kernel(const f16* __restrict__ Xp, const f16* __restrict__ Wsw,
                      const float* __restrict__ bc,
                      f16* __restrict__ c_ws, f16* __restrict__ Xn,
                      const float* __restrict__ obs_t, const float* __restrict__ outprev,
                      int mode, const float* __restrict__ W_emb,
                      const float* __restrict__ b_emb) {
  const int tid = threadIdx.x;
  const int lane = tid & 63;
  const int wn = tid >> 6;           // wave 0..3 = N-position
  const int l15 = lane & 15;
  const int quad = lane >> 4;
  const int sh = wn >> 1, nq = wn & 1;

  // XCD reuse partition: XCD x = id&7 (round-robin dispatch); each XCD owns
  // bm in [(x&3)*16, +16) and bn in [(x>>2)*8, +8); bn fastest within XCD.
  const int id = blockIdx.x;             // 0..1023
  const int x = id & 7, rr0 = id >> 3;   // rr0 0..127
  const int bn = (x >> 2) * 8 + (rr0 & 7);   // 0..15
  const int bm = (x & 3) * 16 + (rr0 >> 3);  // 0..63
  const int slice = bn * 2 + sh;         // 128-col slice this wave reads B from

  float4v acc[4][4];
#pragma unroll
  for (int mi = 0; mi < 4; ++mi)
#pragma unroll
    for (int ni = 0; ni < 4; ++ni) acc[mi][ni] = (float4v){0.f, 0.f, 0.f, 0.f};

  const f16* aB = Xp + (size_t)(bm * 4) * (NKH * 512) + lane * 8;  // +mi*NKH*512 +kh*512
  const f16* bB = Wsw + (size_t)slice * WSL + 2 * 4096 + (nq * 4) * 512 + lane * 8;
                                                                   // +kh*4096 +ni*512

  // ---- emb phase (K 0..63), A computed in-register, B direct from global ----
  {
    float d0[4], d1[4];
#pragma unroll
    for (int mi = 0; mi < 4; ++mi) {
      const int row = (bm * 4 + mi) * 16 + l15;
      if (mode <= 1) {
        const float* o = obs_t + (size_t)row * 2;
        d0[mi] = o[BATCH * 2] - o[0];
        d1[mi] = o[BATCH * 2 + 1] - o[1];
      } else {
        d0[mi] = outprev[(size_t)row * 5 + 0];
        d1[mi] = outprev[(size_t)row * 5 + 1];
      }
    }
#pragma unroll
    for (int kt = 0; kt < 2; ++kt) {
      float w0[8], w1[8], be[8];
#pragma unroll
      for (int e = 0; e < 8; ++e) {
        const int j = kt * 32 + quad * 8 + e;
        w0[e] = W_emb[2 * j];
        w1[e] = W_emb[2 * j + 1];
        be[e] = b_emb[j];
      }
      half8 bfe[4];
#pragma unroll
      for (int ni = 0; ni < 4; ++ni)
        bfe[ni] = *(const half8*)(Wsw + (size_t)slice * WSL + kt * 4096 + (nq * 4 + ni) * 512 + lane * 8);
#pragma unroll
      for (int mi = 0; mi < 4; ++mi) {
        half8 ae;
#pragma unroll
        for (int e = 0; e < 8; ++e)
          ae[e] = (f16)fmaxf(d0[mi] * w0[e] + d1[mi] * w1[e] + be[e], 0.f);
#pragma unroll
        for (int ni = 0; ni < 4; ++ni)
          acc[mi][ni] = __builtin_amdgcn_mfma_f32_16x16x32_f16(ae, bfe[ni], acc[mi][ni], 0, 0, 0);
      }
    }
  }

  // ---- h phase (K-tiles 0..31): fully static unroll, 2-deep reg ping-pong ----
  if (mode != 0) {
    half8 af[2][4], bf[2][4];
#define LOADT(buf, kh)                                                         \
  do {                                                                         \
    _Pragma("unroll") for (int mi = 0; mi < 4; ++mi)                           \
        af[buf][mi] = *(const half8*)(aB + mi * (NKH * 512) + (kh) * 512);     \
    _Pragma("unroll") for (int ni = 0; ni < 4; ++ni)                           \
        bf[buf][ni] = *(const half8*)(bB + (kh) * 4096 + ni * 512);            \
  } while (0)
    LOADT(0, 0);
#pragma unroll
    for (int kh = 0; kh < NKH; ++kh) {
      if (kh + 1 < NKH) LOADT((kh + 1) & 1, kh + 1);
      __builtin_amdgcn_s_setprio(1);
#pragma unroll
      for (int mi = 0; mi < 4; ++mi)
#pragma unroll
        for (int ni = 0; ni < 4; ++ni)
          acc[mi][ni] = __builtin_amdgcn_mfma_f32_16x16x32_f16(af[kh & 1][mi], bf[kh & 1][ni],
                                                               acc[mi][ni], 0, 0, 0);
      __builtin_amdgcn_s_setprio(0);
    }
#undef LOADT
  }

  // ---- epilogue: lane-local LSTM cell + c/Xn writes (no out-proj here) ----
  float bb[4];
#pragma unroll
  for (int ni = 0; ni < 4; ++ni) bb[ni] = bc[bn * 256 + wn * 64 + ni * 16 + l15];

  f16* cbase = c_ws + ((size_t)(bm * 16 + bn) * 256 + tid) * 16;
  half8 cv[2];
  if (mode != 0) {
#pragma unroll
    for (int q = 0; q < 2; ++q) cv[q] = *(const half8*)(cbase + q * 8);
  }

#pragma unroll
  for (int mi = 0; mi < 4; ++mi) {
#pragma unroll
    for (int r = 0; r < 4; ++r) {
      const int row = bm * 64 + mi * 16 + quad * 4 + r;
      const int ci = mi * 4 + r;              // 0..15
      float gi = acc[mi][0][r] + bb[0];
      float gf = acc[mi][1][r] + bb[1];
      float gg = acc[mi][2][r] + bb[2];
      float go = acc[mi][3][r] + bb[3];
      float co = (mode == 0) ? 0.f : (float)cv[ci >> 3][ci & 7];
      float cn = sigm(gf) * co + sigm(gi) * tanh_f(gg);
      cv[ci >> 3][ci & 7] = (f16)cn;
      float h = sigm(go) * tanh_f(cn);
      // h col = u = bn*64+wn*16+l15 ; frag index kh = u>>5 = slice
      Xn[(((size_t)(row >> 4) * NKH + slice) * 64 + (quad * 4 + r) +
          16 * ((wn & 1) * 2 + (l15 >> 3))) * 8 + (l15 & 7)] = (f16)h;
    }
  }
#pragma unroll
  for (int q = 0; q < 2; ++q) *(half8*)(cbase + q * 8) = cv[q];
}

// ---------------------------------------------------------------------------
// out[row][o] = b_out[o] + sum_u h[row][u] * W_out[o][u], reading h from the
// Xn fragment layout. One wave per row; lane covers u-chunks lane and lane+64.
// ---------------------------------------------------------------------------
__global__ __launch_bounds__(256)
void out_kernel(const f16* __restrict__ Xh, const float* __restrict__ W_out,
                const float* __restrict__ b_out, float* __restrict__ out_t) {
  const int tid = threadIdx.x;
  const int lane = tid & 63;
  const int w = tid >> 6;
  const int row = blockIdx.x * 4 + w;  // 0..4095

  float s[5] = {0.f, 0.f, 0.f, 0.f, 0.f};
#pragma unroll
  for (int half = 0; half < 2; ++half) {
    const int u0 = (lane + half * 64) * 8;  // chunk of 8 consecutive u
    const f16* hp = Xh + (((size_t)(row >> 4) * NKH + (u0 >> 5)) * 64 + (row & 15) +
                          16 * (((u0 >> 4) & 1) * 2 + ((u0 >> 3) & 1))) * 8;
    half8 hv = *(const half8*)hp;
#pragma unroll
    for (int o = 0; o < 5; ++o) {
      const float* wp = W_out + o * HID + u0;
      float acc = 0.f;
#pragma unroll
      for (int e = 0; e < 8; ++e) acc += (float)hv[e] * wp[e];
      s[o] += acc;
    }
  }
#pragma unroll
  for (int o = 0; o < 5; ++o) {
    s[o] += __shfl_xor(s[o], 1, 64);
    s[o] += __shfl_xor(s[o], 2, 64);
    s[o] += __shfl_xor(s[o], 4, 64);
    s[o] += __shfl_xor(s[o], 8, 64);
    s[o] += __shfl_xor(s[o], 16, 64);
    s[o] += __shfl_xor(s[o], 32, 64);
  }
  if (lane == 0) {
#pragma unroll
    for (int o = 0; o < 5; ++o) out_t[(size_t)row * 5 + o] = s[o] + b_out[o];
  }
}

// ---------------------------------------------------------------------------
extern "C" void kernel_launch(void* const* d_in, const int* in_sizes, int n_in,
                              void* d_out, int out_size, void* d_ws, size_t ws_size,
                              hipStream_t stream) {
  const float* observed = (const float*)d_in[0];
  const float* W_emb = (const float*)d_in[1];
  const float* b_emb = (const float*)d_in[2];
  const float* W_ih = (const float*)d_in[3];
  const float* b_ih = (const float*)d_in[4];
  const float* W_hh = (const float*)d_in[5];
  const float* b_hh = (const float*)d_in[6];
  const float* W_out = (const float*)d_in[7];
  const float* b_out = (const float*)d_in[8];
  float* out = (float*)d_out;

  uint8_t* ws = (uint8_t*)d_ws;
  const size_t WSW_BYTES = (size_t)32 * WSL * sizeof(f16);           // 8,912,896
  const size_t XH_BYTES = (size_t)256 * NKH * 64 * 8 * sizeof(f16);  // 8 MiB
  f16* Wsw = (f16*)ws;
  float* bc = (float*)(ws + WSW_BYTES);
  f16* X0 = (f16*)(ws + WSW_BYTES + 16384);
  f16* X1 = (f16*)(ws + WSW_BYTES + 16384 + XH_BYTES);
  f16* c_ws = (f16*)(ws + WSW_BYTES + 16384 + 2 * XH_BYTES);

  pack_kernel<<<(32 * WSL) / 256, 256, 0, stream>>>(W_ih, b_ih, W_hh, b_hh, Wsw, bc);

  for (int t = 0; t < NSTEP; ++t) {
    f16* Xc = (t & 1) ? X1 : X0;  // h(t) written here
    f16* Xq = (t & 1) ? X0 : X1;  // h(t-1)
    const int mode = (t == 0) ? 0 : (t < NOBS ? 1 : 2);
    gemm_cell_kernel<<<1024, 256, 0, stream>>>(
        Xq, Wsw, bc, c_ws, Xc,
        observed + (size_t)t * BATCH * 2, out + (size_t)(t - 1) * BATCH * 5,
        mode, W_emb, b_emb);
    out_kernel<<<BATCH / 4, 256, 0, stream>>>(Xc, W_out, b_out, out + (size_t)t * BATCH * 5);
  }
}